// Round 23
// baseline (148.132 us; speedup 1.0000x reference)
//
#include <hip/hip_runtime.h>

// ARMAConv x2 GNN: N=40000, E=640000, F_IN=512, HID=128, NCLS=64
#define F_IN 512
#define HID 128
#define NCLS 64
#define MPAD 40064        // 313 * 128; 626 * 64
#define GB (MPAD / 64)    // 626 gemm1 blocks

typedef __bf16 bf16x8 __attribute__((ext_vector_type(8)));
typedef float f32x4 __attribute__((ext_vector_type(4)));

__device__ __forceinline__ float lo16(unsigned u) {
    unsigned x = u << 16;
    float f;
    __builtin_memcpy(&f, &x, 4);
    return f;
}
__device__ __forceinline__ float hi16(unsigned u) {
    unsigned x = u & 0xffff0000u;
    float f;
    __builtin_memcpy(&f, &x, 4);
    return f;
}

// ---------------- degree count ----------------
__global__ __launch_bounds__(256) void count_kernel(const int* __restrict__ dst,
                                                    int* __restrict__ cnt, int E) {
    int i = blockIdx.x * 256 + threadIdx.x;
    if (i < E) atomicAdd(&cnt[dst[i]], 1);
}

// ---------------- scan stage 1 (+ dinv) ∥ weight prep (independent blocks) ----------------
__global__ __launch_bounds__(1024) void scan1w_kernel(const int* __restrict__ cnt,
                                                      int* __restrict__ rowptr,
                                                      int* __restrict__ bsum,
                                                      float* __restrict__ dinv, int n, int nb,
                                                      const float* __restrict__ W1i,
                                                      const float* __restrict__ W1r,
                                                      const float* __restrict__ W2i,
                                                      const float* __restrict__ W2r,
                                                      __bf16* __restrict__ W1t,
                                                      __bf16* __restrict__ W2t) {
    int bid = blockIdx.x;
    int tid = threadIdx.x;
    if (bid < nb) {  // scan stage 1
        __shared__ int s[1024];
        int i = bid * 1024 + tid;
        int v = (i < n) ? cnt[i] : 0;
        if (i < n) dinv[i] = v > 0 ? rsqrtf((float)v) : 0.f;
        s[tid] = v;
        __syncthreads();
        for (int off = 1; off < 1024; off <<= 1) {
            int t = (tid >= off) ? s[tid - off] : 0;
            __syncthreads();
            s[tid] += t;
            __syncthreads();
        }
        if (i < n) rowptr[i] = s[tid] - v;  // exclusive within block
        if (tid == 1023) bsum[bid] = s[1023];
    } else {  // weight transpose+cast (blocks nb .. nb+383)
        int b = bid - nb;
        if (b < 256) {
            const float* Wsrc = (b < HID) ? W1i : W1r;
            int c = (b < HID) ? b : b - HID;
            for (int k = tid; k < F_IN; k += 1024)
                W1t[(long)b * F_IN + k] = (__bf16)Wsrc[(long)k * HID + c];
        } else {
            int m = b - 256;
            const float* Wsrc = (m < NCLS) ? W2i : W2r;
            int c = (m < NCLS) ? m : m - NCLS;
            for (int k = tid; k < HID; k += 1024)
                W2t[(long)m * HID + k] = (__bf16)Wsrc[(long)k * NCLS + c];
        }
    }
}

// ---------------- scan stage 2+3 ----------------
__global__ __launch_bounds__(1024) void scan23_kernel(int* __restrict__ rowptr,
                                                      const int* __restrict__ bsum, int n) {
    __shared__ int off_s;
    if (threadIdx.x == 0) {
        int run = 0;
        for (int b = 0; b < (int)blockIdx.x; ++b) run += bsum[b];
        off_s = run;
    }
    __syncthreads();
    int i = blockIdx.x * 1024 + threadIdx.x;
    if (i < n) rowptr[i] += off_s;
}

// ---------------- FUSED: gemm1 (blocks 0..GB-1) ∥ CSR fill (blocks GB..) --------------
// r17 tail-append config + BK=128 double-chunk: two 32KB K-64 B-chunks staged per
// phase (smem 64KB, chunk1 at +32768), ONE barrier/drain per 2 K-steps -> 4 drains
// instead of 8. Same verified per-chunk layout/swizzle. gemm1: 64x256 tile, 8 waves
// (4M x 2N, acc[8]), A direct global->reg, split-output epilogue.
__global__ __launch_bounds__(512) void gemm1fill_kernel(const float* __restrict__ A,
                                                        const __bf16* __restrict__ Bt,
                                                        const float* __restrict__ bias,
                                                        __bf16* __restrict__ Hi,
                                                        __bf16* __restrict__ Hr, int M,
                                                        const int* __restrict__ src,
                                                        const int* __restrict__ dst,
                                                        int* __restrict__ rowptr,
                                                        const float* __restrict__ dinv,
                                                        uint2* __restrict__ epk, int E) {
    __shared__ char smem[65536];  // two B chunks of [256 cols][128B] (fill: unused)
    const int tid = threadIdx.x;

    if (blockIdx.x >= GB) {  // ---- fill branch ----
        int e = (blockIdx.x - GB) * 512 + tid;
        if (e < E) {
            int s = src[e];
            int d = dst[e];
            int pos = atomicAdd(&rowptr[d], 1);
            float nr = dinv[s] * dinv[d];
            unsigned nu;
            __builtin_memcpy(&nu, &nr, 4);
            epk[pos] = make_uint2((unsigned)s, nu);
        }
        return;
    }

    // ---- gemm1 branch ----
    const int w = tid >> 6, l = tid & 63;
    const int wm = w >> 1, wn = w & 1;  // 4M x 2N wave grid
    const int lr = l & 15, lg = l >> 4;
    const long m0 = (long)blockIdx.x * 64;

    f32x4 acc[8] = {};

    long arow = m0 + wm * 16 + lr;
    if (arow >= M) arow = M - 1;  // tail clamp: rows >= M never consumed downstream
    const float* aptr = A + arow * F_IN + lg * 8;

    const char* gsrc[4];
    int ldso[4];
#pragma unroll
    for (int j = 0; j < 4; ++j) {
        int q = (tid + j * 512) * 16;  // byte in [0,32768) within a chunk
        int c = q >> 7, off = q & 127;
        gsrc[j] = (const char*)Bt + (long)c * 1024 + (off ^ ((c & 7) << 4));
        ldso[j] = w * 1024 + j * 8192;  // wave-uniform base (HW adds lane*16)
    }

    const int bsw = (lr & 7) << 4;
    int b_off[2][8];
#pragma unroll
    for (int fn = 0; fn < 8; ++fn) {
        int c = wn * 128 + fn * 16 + lr;
#pragma unroll
        for (int kk = 0; kk < 2; ++kk)
            b_off[kk][fn] = c * 128 + ((kk * 64 + lg * 16) ^ bsw);
    }

#pragma unroll
    for (int st = 0; st < 4; ++st) {  // super-step = 2 K-64 steps, ONE drain
        const int kt0 = 2 * st, kt1 = 2 * st + 1;
        // stage both chunks
#pragma unroll
        for (int j = 0; j < 4; ++j)
            __builtin_amdgcn_global_load_lds(
                (const __attribute__((address_space(1))) unsigned*)(const void*)(gsrc[j] + kt0 * 128),
                (__attribute__((address_space(3))) unsigned*)(void*)(smem + ldso[j]), 16, 0, 0);
#pragma unroll
        for (int j = 0; j < 4; ++j)
            __builtin_amdgcn_global_load_lds(
                (const __attribute__((address_space(1))) unsigned*)(const void*)(gsrc[j] + kt1 * 128),
                (__attribute__((address_space(3))) unsigned*)(void*)(smem + 32768 + ldso[j]), 16, 0, 0);
        // A for both K-steps
        float4 ar0 = *reinterpret_cast<const float4*>(aptr + kt0 * 64);
        float4 ar1 = *reinterpret_cast<const float4*>(aptr + kt0 * 64 + 4);
        float4 ar2 = *reinterpret_cast<const float4*>(aptr + kt0 * 64 + 32);
        float4 ar3 = *reinterpret_cast<const float4*>(aptr + kt0 * 64 + 36);
        float4 ar4 = *reinterpret_cast<const float4*>(aptr + kt1 * 64);
        float4 ar5 = *reinterpret_cast<const float4*>(aptr + kt1 * 64 + 4);
        float4 ar6 = *reinterpret_cast<const float4*>(aptr + kt1 * 64 + 32);
        float4 ar7 = *reinterpret_cast<const float4*>(aptr + kt1 * 64 + 36);
        __syncthreads();  // single drain: both chunks in LDS, A in regs

        bf16x8 a0, a1, a2, a3;
        a0[0] = (__bf16)ar0.x; a0[1] = (__bf16)ar0.y; a0[2] = (__bf16)ar0.z; a0[3] = (__bf16)ar0.w;
        a0[4] = (__bf16)ar1.x; a0[5] = (__bf16)ar1.y; a0[6] = (__bf16)ar1.z; a0[7] = (__bf16)ar1.w;
        a1[0] = (__bf16)ar2.x; a1[1] = (__bf16)ar2.y; a1[2] = (__bf16)ar2.z; a1[3] = (__bf16)ar2.w;
        a1[4] = (__bf16)ar3.x; a1[5] = (__bf16)ar3.y; a1[6] = (__bf16)ar3.z; a1[7] = (__bf16)ar3.w;
        a2[0] = (__bf16)ar4.x; a2[1] = (__bf16)ar4.y; a2[2] = (__bf16)ar4.z; a2[3] = (__bf16)ar4.w;
        a2[4] = (__bf16)ar5.x; a2[5] = (__bf16)ar5.y; a2[6] = (__bf16)ar5.z; a2[7] = (__bf16)ar5.w;
        a3[0] = (__bf16)ar6.x; a3[1] = (__bf16)ar6.y; a3[2] = (__bf16)ar6.z; a3[3] = (__bf16)ar6.w;
        a3[4] = (__bf16)ar7.x; a3[5] = (__bf16)ar7.y; a3[6] = (__bf16)ar7.z; a3[7] = (__bf16)ar7.w;
#pragma unroll
        for (int fn = 0; fn < 8; ++fn) {
            bf16x8 vb = *reinterpret_cast<const bf16x8*>(smem + b_off[0][fn]);
            acc[fn] = __builtin_amdgcn_mfma_f32_16x16x32_bf16(a0, vb, acc[fn], 0, 0, 0);
        }
#pragma unroll
        for (int fn = 0; fn < 8; ++fn) {
            bf16x8 vb = *reinterpret_cast<const bf16x8*>(smem + b_off[1][fn]);
            acc[fn] = __builtin_amdgcn_mfma_f32_16x16x32_bf16(a1, vb, acc[fn], 0, 0, 0);
        }
#pragma unroll
        for (int fn = 0; fn < 8; ++fn) {
            bf16x8 vb = *reinterpret_cast<const bf16x8*>(smem + 32768 + b_off[0][fn]);
            acc[fn] = __builtin_amdgcn_mfma_f32_16x16x32_bf16(a2, vb, acc[fn], 0, 0, 0);
        }
#pragma unroll
        for (int fn = 0; fn < 8; ++fn) {
            bf16x8 vb = *reinterpret_cast<const bf16x8*>(smem + 32768 + b_off[1][fn]);
            acc[fn] = __builtin_amdgcn_mfma_f32_16x16x32_bf16(a3, vb, acc[fn], 0, 0, 0);
        }
        if (st < 3) __syncthreads();  // LDS reads done before next overwrite
    }

    // epilogue: C/D col=lane&15, row=(lane>>4)*4+j; wn selects init/root buffer
    __bf16* Hout = wn ? Hr : Hi;
#pragma unroll
    for (int fn = 0; fn < 8; ++fn) {
        int col = fn * 16 + lr;
        float bvv = wn ? bias[col] : 0.f;
        long row = m0 + wm * 16 + lg * 4;
#pragma unroll
        for (int j2 = 0; j2 < 4; ++j2)
            Hout[(row + j2) * 128 + col] = (__bf16)(acc[fn][j2] + bvv);
    }
}

// ---------------- GEMM2 (bf16 A): split-output 64-col halves ----------------
__global__ __launch_bounds__(256) void gemm2_kernel(const __bf16* __restrict__ A,
                                                    const __bf16* __restrict__ Bt,
                                                    const float* __restrict__ bias,
                                                    __bf16* __restrict__ Hi,
                                                    __bf16* __restrict__ Hr) {
    const int K = HID;
    __shared__ char smem[24576];
    const int tid = threadIdx.x;
    const int w = tid >> 6, l = tid & 63;
    const int lr = l & 15, lg = l >> 4;
    const long m0 = (long)blockIdx.x * 128;
    const int n0 = blockIdx.y * 64;
    const long Kb = (long)K * 2;

    f32x4 acc[2][4] = {};

    int a_off[2][2], b_off[2][4];
#pragma unroll
    for (int fm = 0; fm < 2; ++fm) {
        int r = w * 32 + fm * 16 + lr;
        int s = (r & 7) << 4;
#pragma unroll
        for (int kk = 0; kk < 2; ++kk)
            a_off[fm][kk] = r * 128 + ((kk * 64 + lg * 16) ^ s);
    }
#pragma unroll
    for (int fn = 0; fn < 4; ++fn) {
        int c = fn * 16 + lr;
        int s = (c & 7) << 4;
#pragma unroll
        for (int kk = 0; kk < 2; ++kk)
            b_off[kk][fn] = 16384 + c * 128 + ((kk * 64 + lg * 16) ^ s);
    }

    const char* gsrc[6];
    char* ldst[6];
#pragma unroll
    for (int j = 0; j < 6; ++j) {
        int p = (w * 6 + j) * 1024 + l * 16;
        ldst[j] = smem + (w * 6 + j) * 1024;
        if (p < 16384) {
            int row = p >> 7;
            int loff = (p & 127) ^ ((row & 7) << 4);
            gsrc[j] = (const char*)A + (m0 + row) * Kb + loff;
        } else {
            int q = p - 16384;
            int c = q >> 7;
            int loff = (q & 127) ^ ((c & 7) << 4);
            gsrc[j] = (const char*)Bt + (long)(n0 + c) * Kb + loff;
        }
    }

    const int nk = K >> 6;
    for (int kt = 0; kt < nk; ++kt) {
#pragma unroll
        for (int j = 0; j < 6; ++j) {
            __builtin_amdgcn_global_load_lds(
                (const __attribute__((address_space(1))) unsigned*)(const void*)(gsrc[j] + (long)kt * 128),
                (__attribute__((address_space(3))) unsigned*)(void*)ldst[j], 16, 0, 0);
        }
        __syncthreads();
#pragma unroll
        for (int kk = 0; kk < 2; ++kk) {
            bf16x8 av[2], bv[4];
#pragma unroll
            for (int fm = 0; fm < 2; ++fm)
                av[fm] = *reinterpret_cast<const bf16x8*>(smem + a_off[fm][kk]);
#pragma unroll
            for (int fn = 0; fn < 4; ++fn)
                bv[fn] = *reinterpret_cast<const bf16x8*>(smem + b_off[kk][fn]);
#pragma unroll
            for (int fm = 0; fm < 2; ++fm)
#pragma unroll
                for (int fn = 0; fn < 4; ++fn)
                    acc[fm][fn] = __builtin_amdgcn_mfma_f32_16x16x32_bf16(
                        av[fm], bv[fn], acc[fm][fn], 0, 0, 0);
        }
        __syncthreads();
    }

    __bf16* Hout = blockIdx.y ? Hr : Hi;
#pragma unroll
    for (int fn = 0; fn < 4; ++fn) {
        int col = fn * 16 + lr;
        float bvv = blockIdx.y ? bias[col] : 0.f;
#pragma unroll
        for (int fm = 0; fm < 2; ++fm) {
            long row = m0 + w * 32 + fm * 16 + lg * 4;
#pragma unroll
            for (int j2 = 0; j2 < 4; ++j2)
                Hout[(row + j2) * 64 + col] = (__bf16)(acc[fm][fn][j2] + bvv);
        }
    }
}

// ---------------- gather F=128: dense Hinit[M][128], quarter-wave ----------------
__global__ __launch_bounds__(256) void gather128_kernel(const int* __restrict__ rowptr,
                                                        const int* __restrict__ cnt,
                                                        const uint2* __restrict__ epk,
                                                        const unsigned short* __restrict__ Hb,
                                                        const unsigned short* __restrict__ Hroot,
                                                        __bf16* __restrict__ outb, int n) {
    int wid = (blockIdx.x * 256 + threadIdx.x) >> 6;
    int l = threadIdx.x & 63;
    if (wid >= n) return;
    const int len = cnt[wid];
    const int s0 = rowptr[wid] - len;  // rowptr holds end-offsets after fill
    const int li = l & 15, q = l >> 4;

    int sv = 0;
    float nv = 0.f;
    if (l < len) {
        uint2 p = epk[s0 + l];
        sv = (int)p.x;
        nv = __uint_as_float(p.y);
    }
    const int m = len < 64 ? len : 64;
    const int T = (m + 3) >> 2;

    float a[8] = {};
#pragma unroll 4
    for (int t = 0; t < T; ++t) {
        int e = 4 * t + q;
        int s = __shfl(sv, e);
        float nr = __shfl(nv, e);
        uint4 v = *reinterpret_cast<const uint4*>(Hb + (size_t)s * 128 + 8 * li);
        a[0] = fmaf(nr, lo16(v.x), a[0]);
        a[1] = fmaf(nr, hi16(v.x), a[1]);
        a[2] = fmaf(nr, lo16(v.y), a[2]);
        a[3] = fmaf(nr, hi16(v.y), a[3]);
        a[4] = fmaf(nr, lo16(v.z), a[4]);
        a[5] = fmaf(nr, hi16(v.z), a[5]);
        a[6] = fmaf(nr, lo16(v.w), a[6]);
        a[7] = fmaf(nr, hi16(v.w), a[7]);
    }
    for (int k = 64; k < len; ++k) {  // tail: essentially never (Poisson(16))
        if (q == 0) {
            uint2 p = epk[s0 + k];
            int s = (int)p.x;
            float nr = __uint_as_float(p.y);
            uint4 v = *reinterpret_cast<const uint4*>(Hb + (size_t)s * 128 + 8 * li);
            a[0] = fmaf(nr, lo16(v.x), a[0]);
            a[1] = fmaf(nr, hi16(v.x), a[1]);
            a[2] = fmaf(nr, lo16(v.y), a[2]);
            a[3] = fmaf(nr, hi16(v.y), a[3]);
            a[4] = fmaf(nr, lo16(v.z), a[4]);
            a[5] = fmaf(nr, hi16(v.z), a[5]);
            a[6] = fmaf(nr, lo16(v.w), a[6]);
            a[7] = fmaf(nr, hi16(v.w), a[7]);
        }
    }
#pragma unroll
    for (int i = 0; i < 8; ++i) {
        a[i] += __shfl_xor(a[i], 16);
        a[i] += __shfl_xor(a[i], 32);
    }
    if (l < 16) {
        uint4 rv = *reinterpret_cast<const uint4*>(Hroot + (size_t)wid * 128 + 8 * l);
        float r[8] = {lo16(rv.x), hi16(rv.x), lo16(rv.y), hi16(rv.y),
                      lo16(rv.z), hi16(rv.z), lo16(rv.w), hi16(rv.w)};
        union { uint4 v; __bf16 b[8]; } o;
#pragma unroll
        for (int i = 0; i < 8; ++i) o.b[i] = (__bf16)fmaxf(a[i] + r[i], 0.f);
        *reinterpret_cast<uint4*>(outb + (size_t)wid * 128 + 8 * l) = o.v;
    }
}

// ---------------- gather F=64: dense H2init[M][64], fp32 out ----------------
__global__ __launch_bounds__(256) void gather64_kernel(const int* __restrict__ rowptr,
                                                       const int* __restrict__ cnt,
                                                       const uint2* __restrict__ epk,
                                                       const unsigned short* __restrict__ Hb,
                                                       const unsigned short* __restrict__ Hroot,
                                                       float* __restrict__ out, int n) {
    int wid = (blockIdx.x * 256 + threadIdx.x) >> 6;
    int l = threadIdx.x & 63;
    if (wid >= n) return;
    const int len = cnt[wid];
    const int s0 = rowptr[wid] - len;
    const int li = l & 15, q = l >> 4;

    int sv = 0;
    float nv = 0.f;
    if (l < len) {
        uint2 p = epk[s0 + l];
        sv = (int)p.x;
        nv = __uint_as_float(p.y);
    }
    const int m = len < 64 ? len : 64;
    const int T = (m + 3) >> 2;

    float a[4] = {};
#pragma unroll 4
    for (int t = 0; t < T; ++t) {
        int e = 4 * t + q;
        int s = __shfl(sv, e);
        float nr = __shfl(nv, e);
        uint2 v = *reinterpret_cast<const uint2*>(Hb + (size_t)s * 64 + 4 * li);
        a[0] = fmaf(nr, lo16(v.x), a[0]);
        a[1] = fmaf(nr, hi16(v.x), a[1]);
        a[2] = fmaf(nr, lo16(v.y), a[2]);
        a[3] = fmaf(nr, hi16(v.y), a[3]);
    }
    for (int k = 64; k < len; ++k) {
        if (q == 0) {
            uint2 p = epk[s0 + k];
            int s = (int)p.x;
            float nr = __uint_as_float(p.y);
            uint2 v = *reinterpret_cast<const uint2*>(Hb + (size_t)s * 64 + 4 * li);
            a[0] = fmaf(nr, lo16(v.x), a[0]);
            a[1] = fmaf(nr, hi16(v.x), a[1]);
            a[2] = fmaf(nr, lo16(v.y), a[2]);
            a[3] = fmaf(nr, hi16(v.y), a[3]);
        }
    }
#pragma unroll
    for (int i = 0; i < 4; ++i) {
        a[i] += __shfl_xor(a[i], 16);
        a[i] += __shfl_xor(a[i], 32);
    }
    if (l < 16) {
        uint2 rv = *reinterpret_cast<const uint2*>(Hroot + (size_t)wid * 64 + 4 * l);
        float4 o;
        o.x = fmaxf(a[0] + lo16(rv.x), 0.f);
        o.y = fmaxf(a[1] + hi16(rv.x), 0.f);
        o.z = fmaxf(a[2] + lo16(rv.y), 0.f);
        o.w = fmaxf(a[3] + hi16(rv.y), 0.f);
        *reinterpret_cast<float4*>(out + (size_t)wid * 64 + 4 * l) = o;
    }
}

extern "C" void kernel_launch(void* const* d_in, const int* in_sizes, int n_in,
                              void* d_out, int out_size, void* d_ws, size_t ws_size,
                              hipStream_t stream) {
    const float* x   = (const float*)d_in[0];
    const float* W1i = (const float*)d_in[1];
    const float* W1r = (const float*)d_in[2];
    const float* b1  = (const float*)d_in[3];
    const float* W2i = (const float*)d_in[4];
    const float* W2r = (const float*)d_in[5];
    const float* b2  = (const float*)d_in[6];
    const int*   ei  = (const int*)d_in[7];

    const int E = in_sizes[7] / 2;
    const int M = in_sizes[0] / F_IN;  // 40000
    const int* src = ei;
    const int* dst = ei + E;

    char* w = (char*)d_ws;
    int*    cnt    = (int*)w;            w += 40960 * 4;
    int*    rowptr = (int*)w;            w += 40960 * 4;
    float*  dinv   = (float*)w;          w += 40960 * 4;
    int*    bsum   = (int*)w;            w += 4096;
    uint2*  epk    = (uint2*)w;          w += (size_t)E * 8;
    __bf16* W1t    = (__bf16*)w;         w += 256 * 512 * 2;
    __bf16* W2t    = (__bf16*)w;         w += 128 * 128 * 2;
    __bf16* H1i    = (__bf16*)w;         w += (size_t)MPAD * 128 * 2;  // 10.25MB dense init
    __bf16* H1r    = (__bf16*)w;         w += (size_t)MPAD * 128 * 2;
    __bf16* out1b  = (__bf16*)w;         w += (size_t)MPAD * 128 * 2;
    __bf16* H2i    = (__bf16*)w;         w += (size_t)MPAD * 64 * 2;   // 5.1MB dense init
    __bf16* H2r    = (__bf16*)w;         w += (size_t)MPAD * 64 * 2;
    float*  outp   = (float*)d_out;

    const int nb = (M + 1023) / 1024;  // 40
    const int fill_blocks = (E + 511) / 512;  // 1250

    // ---- CSR build (W-prep hidden in scan1's launch) ----
    hipMemsetAsync(cnt, 0, (size_t)M * sizeof(int), stream);
    count_kernel<<<(E + 255) / 256, 256, 0, stream>>>(dst, cnt, E);
    scan1w_kernel<<<nb + 384, 1024, 0, stream>>>(cnt, rowptr, bsum, dinv, M, nb,
                                                 W1i, W1r, W2i, W2r, W1t, W2t);
    scan23_kernel<<<nb, 1024, 0, stream>>>(rowptr, bsum, M);

    // ---- layer 1: gemm1 (BK=128 double-chunk) with fill appended ----
    gemm1fill_kernel<<<GB + fill_blocks, 512, 0, stream>>>(
        x, W1t, b1, H1i, H1r, M, src, dst, rowptr, dinv, epk, E);
    gather128_kernel<<<(M * 64 + 255) / 256, 256, 0, stream>>>(
        rowptr, cnt, epk, (const unsigned short*)H1i, (const unsigned short*)H1r, out1b, M);

    // ---- layer 2 ----
    gemm2_kernel<<<dim3(MPAD / 128, 2), 256, 0, stream>>>(out1b, W2t, b2, H2i, H2r);
    gather64_kernel<<<(M * 64 + 255) / 256, 256, 0, stream>>>(
        rowptr, cnt, epk, (const unsigned short*)H2i, (const unsigned short*)H2r, outp, M);
}

// Round 24
// 143.436 us; speedup vs baseline: 1.0327x; 1.0327x over previous
//
#include <hip/hip_runtime.h>

// ARMAConv x2 GNN: N=40000, E=640000, F_IN=512, HID=128, NCLS=64
#define F_IN 512
#define HID 128
#define NCLS 64
#define MPAD 40064        // 313 * 128; 626 * 64
#define GB (MPAD / 64)    // 626 gemm1 blocks

typedef __bf16 bf16x8 __attribute__((ext_vector_type(8)));
typedef float f32x4 __attribute__((ext_vector_type(4)));

__device__ __forceinline__ float lo16(unsigned u) {
    unsigned x = u << 16;
    float f;
    __builtin_memcpy(&f, &x, 4);
    return f;
}
__device__ __forceinline__ float hi16(unsigned u) {
    unsigned x = u & 0xffff0000u;
    float f;
    __builtin_memcpy(&f, &x, 4);
    return f;
}

// ---------------- degree count ----------------
__global__ __launch_bounds__(256) void count_kernel(const int* __restrict__ dst,
                                                    int* __restrict__ cnt, int E) {
    int i = blockIdx.x * 256 + threadIdx.x;
    if (i < E) atomicAdd(&cnt[dst[i]], 1);
}

// ---------------- scan stage 1 (+ dinv) ∥ weight prep (independent blocks) ----------------
__global__ __launch_bounds__(1024) void scan1w_kernel(const int* __restrict__ cnt,
                                                      int* __restrict__ rowptr,
                                                      int* __restrict__ bsum,
                                                      float* __restrict__ dinv, int n, int nb,
                                                      const float* __restrict__ W1i,
                                                      const float* __restrict__ W1r,
                                                      const float* __restrict__ W2i,
                                                      const float* __restrict__ W2r,
                                                      __bf16* __restrict__ W1t,
                                                      __bf16* __restrict__ W2t) {
    int bid = blockIdx.x;
    int tid = threadIdx.x;
    if (bid < nb) {  // scan stage 1
        __shared__ int s[1024];
        int i = bid * 1024 + tid;
        int v = (i < n) ? cnt[i] : 0;
        if (i < n) dinv[i] = v > 0 ? rsqrtf((float)v) : 0.f;
        s[tid] = v;
        __syncthreads();
        for (int off = 1; off < 1024; off <<= 1) {
            int t = (tid >= off) ? s[tid - off] : 0;
            __syncthreads();
            s[tid] += t;
            __syncthreads();
        }
        if (i < n) rowptr[i] = s[tid] - v;  // exclusive within block
        if (tid == 1023) bsum[bid] = s[1023];
    } else {  // weight transpose+cast (blocks nb .. nb+383)
        int b = bid - nb;
        if (b < 256) {
            const float* Wsrc = (b < HID) ? W1i : W1r;
            int c = (b < HID) ? b : b - HID;
            for (int k = tid; k < F_IN; k += 1024)
                W1t[(long)b * F_IN + k] = (__bf16)Wsrc[(long)k * HID + c];
        } else {
            int m = b - 256;
            const float* Wsrc = (m < NCLS) ? W2i : W2r;
            int c = (m < NCLS) ? m : m - NCLS;
            for (int k = tid; k < HID; k += 1024)
                W2t[(long)m * HID + k] = (__bf16)Wsrc[(long)k * NCLS + c];
        }
    }
}

// ---------------- scan stage 2+3 ----------------
__global__ __launch_bounds__(1024) void scan23_kernel(int* __restrict__ rowptr,
                                                      const int* __restrict__ bsum, int n) {
    __shared__ int off_s;
    if (threadIdx.x == 0) {
        int run = 0;
        for (int b = 0; b < (int)blockIdx.x; ++b) run += bsum[b];
        off_s = run;
    }
    __syncthreads();
    int i = blockIdx.x * 1024 + threadIdx.x;
    if (i < n) rowptr[i] += off_s;
}

// ---------------- FUSED: gemm1 (blocks 0..GB-1) ∥ CSR fill (blocks GB..) --------------
// r20 measured-best configuration (143.6us total, reproduced twice): fill blocks
// appended AFTER gemm1 blocks (r18 interleave regressed: fill displaces gemm1 waves).
// gemm1: 64x256 tile, 8 waves (4M x 2N, acc[8]), B single 32KB LDS buffer (best of
// 8 schedule variants at this skinny shape), A direct global->reg, syncthreads drain,
// split-output epilogue (wn=0 -> Hi, wn=1 -> Hr+bias).
__global__ __launch_bounds__(512) void gemm1fill_kernel(const float* __restrict__ A,
                                                        const __bf16* __restrict__ Bt,
                                                        const float* __restrict__ bias,
                                                        __bf16* __restrict__ Hi,
                                                        __bf16* __restrict__ Hr, int M,
                                                        const int* __restrict__ src,
                                                        const int* __restrict__ dst,
                                                        int* __restrict__ rowptr,
                                                        const float* __restrict__ dinv,
                                                        uint2* __restrict__ epk, int E) {
    __shared__ char smem[32768];  // B tile [256 cols][128B] (fill blocks: unused)
    const int tid = threadIdx.x;

    if (blockIdx.x >= GB) {  // ---- fill branch ----
        int e = (blockIdx.x - GB) * 512 + tid;
        if (e < E) {
            int s = src[e];
            int d = dst[e];
            int pos = atomicAdd(&rowptr[d], 1);
            float nr = dinv[s] * dinv[d];
            unsigned nu;
            __builtin_memcpy(&nu, &nr, 4);
            epk[pos] = make_uint2((unsigned)s, nu);
        }
        return;
    }

    // ---- gemm1 branch ----
    const int w = tid >> 6, l = tid & 63;
    const int wm = w >> 1, wn = w & 1;  // 4M x 2N wave grid
    const int lr = l & 15, lg = l >> 4;
    const long m0 = (long)blockIdx.x * 64;

    f32x4 acc[8] = {};

    long arow = m0 + wm * 16 + lr;
    if (arow >= M) arow = M - 1;  // tail clamp: rows >= M never consumed downstream
    const float* aptr = A + arow * F_IN + lg * 8;

    const char* gsrc[4];
    int ldso[4];
#pragma unroll
    for (int j = 0; j < 4; ++j) {
        int q = (tid + j * 512) * 16;  // byte in [0,32768)
        int c = q >> 7, off = q & 127;
        gsrc[j] = (const char*)Bt + (long)c * 1024 + (off ^ ((c & 7) << 4));
        ldso[j] = w * 1024 + j * 8192;  // wave-uniform base (HW adds lane*16)
    }

    const int bsw = (lr & 7) << 4;
    int b_off[2][8];
#pragma unroll
    for (int fn = 0; fn < 8; ++fn) {
        int c = wn * 128 + fn * 16 + lr;
#pragma unroll
        for (int kk = 0; kk < 2; ++kk)
            b_off[kk][fn] = c * 128 + ((kk * 64 + lg * 16) ^ bsw);
    }

#pragma unroll
    for (int kt = 0; kt < 8; ++kt) {
#pragma unroll
        for (int j = 0; j < 4; ++j)
            __builtin_amdgcn_global_load_lds(
                (const __attribute__((address_space(1))) unsigned*)(const void*)(gsrc[j] + kt * 128),
                (__attribute__((address_space(3))) unsigned*)(void*)(smem + ldso[j]), 16, 0, 0);
        float4 ar0 = *reinterpret_cast<const float4*>(aptr + kt * 64);
        float4 ar1 = *reinterpret_cast<const float4*>(aptr + kt * 64 + 4);
        float4 ar2 = *reinterpret_cast<const float4*>(aptr + kt * 64 + 32);
        float4 ar3 = *reinterpret_cast<const float4*>(aptr + kt * 64 + 36);
        __syncthreads();  // B in LDS, A in regs

        bf16x8 a0, a1;
        a0[0] = (__bf16)ar0.x; a0[1] = (__bf16)ar0.y; a0[2] = (__bf16)ar0.z; a0[3] = (__bf16)ar0.w;
        a0[4] = (__bf16)ar1.x; a0[5] = (__bf16)ar1.y; a0[6] = (__bf16)ar1.z; a0[7] = (__bf16)ar1.w;
        a1[0] = (__bf16)ar2.x; a1[1] = (__bf16)ar2.y; a1[2] = (__bf16)ar2.z; a1[3] = (__bf16)ar2.w;
        a1[4] = (__bf16)ar3.x; a1[5] = (__bf16)ar3.y; a1[6] = (__bf16)ar3.z; a1[7] = (__bf16)ar3.w;
#pragma unroll
        for (int fn = 0; fn < 8; ++fn) {
            bf16x8 vb = *reinterpret_cast<const bf16x8*>(smem + b_off[0][fn]);
            acc[fn] = __builtin_amdgcn_mfma_f32_16x16x32_bf16(a0, vb, acc[fn], 0, 0, 0);
        }
#pragma unroll
        for (int fn = 0; fn < 8; ++fn) {
            bf16x8 vb = *reinterpret_cast<const bf16x8*>(smem + b_off[1][fn]);
            acc[fn] = __builtin_amdgcn_mfma_f32_16x16x32_bf16(a1, vb, acc[fn], 0, 0, 0);
        }
        if (kt < 7) __syncthreads();
    }

    // epilogue: C/D col=lane&15, row=(lane>>4)*4+j; wn selects init/root buffer
    __bf16* Hout = wn ? Hr : Hi;
#pragma unroll
    for (int fn = 0; fn < 8; ++fn) {
        int col = fn * 16 + lr;
        float bvv = wn ? bias[col] : 0.f;
        long row = m0 + wm * 16 + lg * 4;
#pragma unroll
        for (int j2 = 0; j2 < 4; ++j2)
            Hout[(row + j2) * 128 + col] = (__bf16)(acc[fn][j2] + bvv);
    }
}

// ---------------- GEMM2 (bf16 A): split-output 64-col halves ----------------
__global__ __launch_bounds__(256) void gemm2_kernel(const __bf16* __restrict__ A,
                                                    const __bf16* __restrict__ Bt,
                                                    const float* __restrict__ bias,
                                                    __bf16* __restrict__ Hi,
                                                    __bf16* __restrict__ Hr) {
    const int K = HID;
    __shared__ char smem[24576];
    const int tid = threadIdx.x;
    const int w = tid >> 6, l = tid & 63;
    const int lr = l & 15, lg = l >> 4;
    const long m0 = (long)blockIdx.x * 128;
    const int n0 = blockIdx.y * 64;
    const long Kb = (long)K * 2;

    f32x4 acc[2][4] = {};

    int a_off[2][2], b_off[2][4];
#pragma unroll
    for (int fm = 0; fm < 2; ++fm) {
        int r = w * 32 + fm * 16 + lr;
        int s = (r & 7) << 4;
#pragma unroll
        for (int kk = 0; kk < 2; ++kk)
            a_off[fm][kk] = r * 128 + ((kk * 64 + lg * 16) ^ s);
    }
#pragma unroll
    for (int fn = 0; fn < 4; ++fn) {
        int c = fn * 16 + lr;
        int s = (c & 7) << 4;
#pragma unroll
        for (int kk = 0; kk < 2; ++kk)
            b_off[kk][fn] = 16384 + c * 128 + ((kk * 64 + lg * 16) ^ s);
    }

    const char* gsrc[6];
    char* ldst[6];
#pragma unroll
    for (int j = 0; j < 6; ++j) {
        int p = (w * 6 + j) * 1024 + l * 16;
        ldst[j] = smem + (w * 6 + j) * 1024;
        if (p < 16384) {
            int row = p >> 7;
            int loff = (p & 127) ^ ((row & 7) << 4);
            gsrc[j] = (const char*)A + (m0 + row) * Kb + loff;
        } else {
            int q = p - 16384;
            int c = q >> 7;
            int loff = (q & 127) ^ ((c & 7) << 4);
            gsrc[j] = (const char*)Bt + (long)(n0 + c) * Kb + loff;
        }
    }

    const int nk = K >> 6;
    for (int kt = 0; kt < nk; ++kt) {
#pragma unroll
        for (int j = 0; j < 6; ++j) {
            __builtin_amdgcn_global_load_lds(
                (const __attribute__((address_space(1))) unsigned*)(const void*)(gsrc[j] + (long)kt * 128),
                (__attribute__((address_space(3))) unsigned*)(void*)ldst[j], 16, 0, 0);
        }
        __syncthreads();
#pragma unroll
        for (int kk = 0; kk < 2; ++kk) {
            bf16x8 av[2], bv[4];
#pragma unroll
            for (int fm = 0; fm < 2; ++fm)
                av[fm] = *reinterpret_cast<const bf16x8*>(smem + a_off[fm][kk]);
#pragma unroll
            for (int fn = 0; fn < 4; ++fn)
                bv[fn] = *reinterpret_cast<const bf16x8*>(smem + b_off[kk][fn]);
#pragma unroll
            for (int fm = 0; fm < 2; ++fm)
#pragma unroll
                for (int fn = 0; fn < 4; ++fn)
                    acc[fm][fn] = __builtin_amdgcn_mfma_f32_16x16x32_bf16(
                        av[fm], bv[fn], acc[fm][fn], 0, 0, 0);
        }
        __syncthreads();
    }

    __bf16* Hout = blockIdx.y ? Hr : Hi;
#pragma unroll
    for (int fn = 0; fn < 4; ++fn) {
        int col = fn * 16 + lr;
        float bvv = blockIdx.y ? bias[col] : 0.f;
#pragma unroll
        for (int fm = 0; fm < 2; ++fm) {
            long row = m0 + w * 32 + fm * 16 + lg * 4;
#pragma unroll
            for (int j2 = 0; j2 < 4; ++j2)
                Hout[(row + j2) * 64 + col] = (__bf16)(acc[fm][fn][j2] + bvv);
        }
    }
}

// ---------------- gather F=128: dense Hinit[M][128], quarter-wave ----------------
__global__ __launch_bounds__(256) void gather128_kernel(const int* __restrict__ rowptr,
                                                        const int* __restrict__ cnt,
                                                        const uint2* __restrict__ epk,
                                                        const unsigned short* __restrict__ Hb,
                                                        const unsigned short* __restrict__ Hroot,
                                                        __bf16* __restrict__ outb, int n) {
    int wid = (blockIdx.x * 256 + threadIdx.x) >> 6;
    int l = threadIdx.x & 63;
    if (wid >= n) return;
    const int len = cnt[wid];
    const int s0 = rowptr[wid] - len;  // rowptr holds end-offsets after fill
    const int li = l & 15, q = l >> 4;

    int sv = 0;
    float nv = 0.f;
    if (l < len) {
        uint2 p = epk[s0 + l];
        sv = (int)p.x;
        nv = __uint_as_float(p.y);
    }
    const int m = len < 64 ? len : 64;
    const int T = (m + 3) >> 2;

    float a[8] = {};
#pragma unroll 4
    for (int t = 0; t < T; ++t) {
        int e = 4 * t + q;
        int s = __shfl(sv, e);
        float nr = __shfl(nv, e);
        uint4 v = *reinterpret_cast<const uint4*>(Hb + (size_t)s * 128 + 8 * li);
        a[0] = fmaf(nr, lo16(v.x), a[0]);
        a[1] = fmaf(nr, hi16(v.x), a[1]);
        a[2] = fmaf(nr, lo16(v.y), a[2]);
        a[3] = fmaf(nr, hi16(v.y), a[3]);
        a[4] = fmaf(nr, lo16(v.z), a[4]);
        a[5] = fmaf(nr, hi16(v.z), a[5]);
        a[6] = fmaf(nr, lo16(v.w), a[6]);
        a[7] = fmaf(nr, hi16(v.w), a[7]);
    }
    for (int k = 64; k < len; ++k) {  // tail: essentially never (Poisson(16))
        if (q == 0) {
            uint2 p = epk[s0 + k];
            int s = (int)p.x;
            float nr = __uint_as_float(p.y);
            uint4 v = *reinterpret_cast<const uint4*>(Hb + (size_t)s * 128 + 8 * li);
            a[0] = fmaf(nr, lo16(v.x), a[0]);
            a[1] = fmaf(nr, hi16(v.x), a[1]);
            a[2] = fmaf(nr, lo16(v.y), a[2]);
            a[3] = fmaf(nr, hi16(v.y), a[3]);
            a[4] = fmaf(nr, lo16(v.z), a[4]);
            a[5] = fmaf(nr, hi16(v.z), a[5]);
            a[6] = fmaf(nr, lo16(v.w), a[6]);
            a[7] = fmaf(nr, hi16(v.w), a[7]);
        }
    }
#pragma unroll
    for (int i = 0; i < 8; ++i) {
        a[i] += __shfl_xor(a[i], 16);
        a[i] += __shfl_xor(a[i], 32);
    }
    if (l < 16) {
        uint4 rv = *reinterpret_cast<const uint4*>(Hroot + (size_t)wid * 128 + 8 * l);
        float r[8] = {lo16(rv.x), hi16(rv.x), lo16(rv.y), hi16(rv.y),
                      lo16(rv.z), hi16(rv.z), lo16(rv.w), hi16(rv.w)};
        union { uint4 v; __bf16 b[8]; } o;
#pragma unroll
        for (int i = 0; i < 8; ++i) o.b[i] = (__bf16)fmaxf(a[i] + r[i], 0.f);
        *reinterpret_cast<uint4*>(outb + (size_t)wid * 128 + 8 * l) = o.v;
    }
}

// ---------------- gather F=64: dense H2init[M][64], fp32 out ----------------
__global__ __launch_bounds__(256) void gather64_kernel(const int* __restrict__ rowptr,
                                                       const int* __restrict__ cnt,
                                                       const uint2* __restrict__ epk,
                                                       const unsigned short* __restrict__ Hb,
                                                       const unsigned short* __restrict__ Hroot,
                                                       float* __restrict__ out, int n) {
    int wid = (blockIdx.x * 256 + threadIdx.x) >> 6;
    int l = threadIdx.x & 63;
    if (wid >= n) return;
    const int len = cnt[wid];
    const int s0 = rowptr[wid] - len;
    const int li = l & 15, q = l >> 4;

    int sv = 0;
    float nv = 0.f;
    if (l < len) {
        uint2 p = epk[s0 + l];
        sv = (int)p.x;
        nv = __uint_as_float(p.y);
    }
    const int m = len < 64 ? len : 64;
    const int T = (m + 3) >> 2;

    float a[4] = {};
#pragma unroll 4
    for (int t = 0; t < T; ++t) {
        int e = 4 * t + q;
        int s = __shfl(sv, e);
        float nr = __shfl(nv, e);
        uint2 v = *reinterpret_cast<const uint2*>(Hb + (size_t)s * 64 + 4 * li);
        a[0] = fmaf(nr, lo16(v.x), a[0]);
        a[1] = fmaf(nr, hi16(v.x), a[1]);
        a[2] = fmaf(nr, lo16(v.y), a[2]);
        a[3] = fmaf(nr, hi16(v.y), a[3]);
    }
    for (int k = 64; k < len; ++k) {
        if (q == 0) {
            uint2 p = epk[s0 + k];
            int s = (int)p.x;
            float nr = __uint_as_float(p.y);
            uint2 v = *reinterpret_cast<const uint2*>(Hb + (size_t)s * 64 + 4 * li);
            a[0] = fmaf(nr, lo16(v.x), a[0]);
            a[1] = fmaf(nr, hi16(v.x), a[1]);
            a[2] = fmaf(nr, lo16(v.y), a[2]);
            a[3] = fmaf(nr, hi16(v.y), a[3]);
        }
    }
#pragma unroll
    for (int i = 0; i < 4; ++i) {
        a[i] += __shfl_xor(a[i], 16);
        a[i] += __shfl_xor(a[i], 32);
    }
    if (l < 16) {
        uint2 rv = *reinterpret_cast<const uint2*>(Hroot + (size_t)wid * 64 + 4 * l);
        float4 o;
        o.x = fmaxf(a[0] + lo16(rv.x), 0.f);
        o.y = fmaxf(a[1] + hi16(rv.x), 0.f);
        o.z = fmaxf(a[2] + lo16(rv.y), 0.f);
        o.w = fmaxf(a[3] + hi16(rv.y), 0.f);
        *reinterpret_cast<float4*>(out + (size_t)wid * 64 + 4 * l) = o;
    }
}

extern "C" void kernel_launch(void* const* d_in, const int* in_sizes, int n_in,
                              void* d_out, int out_size, void* d_ws, size_t ws_size,
                              hipStream_t stream) {
    const float* x   = (const float*)d_in[0];
    const float* W1i = (const float*)d_in[1];
    const float* W1r = (const float*)d_in[2];
    const float* b1  = (const float*)d_in[3];
    const float* W2i = (const float*)d_in[4];
    const float* W2r = (const float*)d_in[5];
    const float* b2  = (const float*)d_in[6];
    const int*   ei  = (const int*)d_in[7];

    const int E = in_sizes[7] / 2;
    const int M = in_sizes[0] / F_IN;  // 40000
    const int* src = ei;
    const int* dst = ei + E;

    char* w = (char*)d_ws;
    int*    cnt    = (int*)w;            w += 40960 * 4;
    int*    rowptr = (int*)w;            w += 40960 * 4;
    float*  dinv   = (float*)w;          w += 40960 * 4;
    int*    bsum   = (int*)w;            w += 4096;
    uint2*  epk    = (uint2*)w;          w += (size_t)E * 8;
    __bf16* W1t    = (__bf16*)w;         w += 256 * 512 * 2;
    __bf16* W2t    = (__bf16*)w;         w += 128 * 128 * 2;
    __bf16* H1i    = (__bf16*)w;         w += (size_t)MPAD * 128 * 2;  // 10.25MB dense init
    __bf16* H1r    = (__bf16*)w;         w += (size_t)MPAD * 128 * 2;
    __bf16* out1b  = (__bf16*)w;         w += (size_t)MPAD * 128 * 2;
    __bf16* H2i    = (__bf16*)w;         w += (size_t)MPAD * 64 * 2;   // 5.1MB dense init
    __bf16* H2r    = (__bf16*)w;         w += (size_t)MPAD * 64 * 2;
    float*  outp   = (float*)d_out;

    const int nb = (M + 1023) / 1024;  // 40
    const int fill_blocks = (E + 511) / 512;  // 1250

    // ---- CSR build (W-prep hidden in scan1's launch) ----
    hipMemsetAsync(cnt, 0, (size_t)M * sizeof(int), stream);
    count_kernel<<<(E + 255) / 256, 256, 0, stream>>>(dst, cnt, E);
    scan1w_kernel<<<nb + 384, 1024, 0, stream>>>(cnt, rowptr, bsum, dinv, M, nb,
                                                 W1i, W1r, W2i, W2r, W1t, W2t);
    scan23_kernel<<<nb, 1024, 0, stream>>>(rowptr, bsum, M);

    // ---- layer 1: gemm1 with fill appended (same dispatch, no gap) ----
    gemm1fill_kernel<<<GB + fill_blocks, 512, 0, stream>>>(
        x, W1t, b1, H1i, H1r, M, src, dst, rowptr, dinv, epk, E);
    gather128_kernel<<<(M * 64 + 255) / 256, 256, 0, stream>>>(
        rowptr, cnt, epk, (const unsigned short*)H1i, (const unsigned short*)H1r, out1b, M);

    // ---- layer 2 ----
    gemm2_kernel<<<dim3(MPAD / 128, 2), 256, 0, stream>>>(out1b, W2t, b2, H2i, H2r);
    gather64_kernel<<<(M * 64 + 255) / 256, 256, 0, stream>>>(
        rowptr, cnt, epk, (const unsigned short*)H2i, (const unsigned short*)H2r, outp, M);
}